// Round 4
// baseline (1046.789 us; speedup 1.0000x reference)
//
#include <hip/hip_runtime.h>
#include <hip/hip_bf16.h>
#include <stdint.h>

#define M_TOTAL 16384
#define N_TOTAL 4096
#define K_TOTAL 4096

typedef __attribute__((ext_vector_type(8))) short bf16x8;
typedef __attribute__((ext_vector_type(4))) float f32x4;

// ---------------------------------------------------------------------------
// Kernel 1: dequantize packed int4 -> bf16 W[N][K] in workspace.
// word j of row n: k=2j (low nibble), k=2j+1 (high nibble); codes 0..15 -> -8..7
// scaled by scales[n][k/32] (scales are FLOAT32 on device).
// 1 thread -> 8 words -> 16 bf16 (half a scale block, never crosses one).
// ---------------------------------------------------------------------------
__global__ __launch_bounds__(256) void k_dequant(const int* __restrict__ pw,
                                                 const float* __restrict__ sc,
                                                 __hip_bfloat16* __restrict__ W) {
    int t = blockIdx.x * 256 + threadIdx.x;
    int row = t >> 8;                 // 256 threads per row of 2048 words
    int w0 = (t & 255) << 3;          // word offset within row (multiple of 8)
    const int* p = pw + (size_t)row * 2048 + w0;
    int4 q0 = *(const int4*)p;
    int4 q1 = *(const int4*)(p + 4);
    float s = sc[row * 128 + (w0 >> 4)];
    float ns8 = -8.0f * s;
    int w[8] = {q0.x, q0.y, q0.z, q0.w, q1.x, q1.y, q1.z, q1.w};
    __hip_bfloat162 o[8];
#pragma unroll
    for (int i = 0; i < 8; ++i) {
        float lo = fmaf((float)(w[i] & 15), s, ns8);
        float hi = fmaf((float)(w[i] >> 4), s, ns8);   // words are 0..255
        o[i] = __float22bfloat162_rn(make_float2(lo, hi));
    }
    __hip_bfloat16* dst = W + (size_t)row * 4096 + w0 * 2;
    *(int4*)dst = *(int4*)&o[0];
    *(int4*)(dst + 8) = *(int4*)&o[4];
}

// ---------------------------------------------------------------------------
// Kernel 2: GEMM out[m][n] = sum_k X[m][k]*W[n][k].  X f32 -> bf16 in staging,
// W bf16 (PRE) or fused-dequant from packed int4 (!PRE). 128x128 tile, BK=32,
// 256 threads (4 waves 2x2), 4x4 frags of mfma_f32_16x16x32_bf16 per wave.
// Reg-staged with 1-deep prefetch. Output f32.
// ---------------------------------------------------------------------------
template <bool PRE>
__global__ __launch_bounds__(256) void k_gemm(const float* __restrict__ X,
                                              const __hip_bfloat16* __restrict__ Wb,
                                              const int* __restrict__ pw,
                                              const float* __restrict__ sc,
                                              float* __restrict__ out) {
    __shared__ __align__(16) short As[128 * 32];
    __shared__ __align__(16) short Bs[128 * 32];

    int bid = blockIdx.x;
    int bn = bid & 31;            // N tiles fastest -> 32 consecutive blocks share A panel
    int bm = bid >> 5;
    int m0 = bm * 128, n0 = bn * 128;
    int t = threadIdx.x;
    int lane = t & 63;
    int wv = t >> 6;
    int wr = wv >> 1, wc = wv & 1;

    f32x4 acc[4][4];
#pragma unroll
    for (int i = 0; i < 4; ++i)
#pragma unroll
        for (int j = 0; j < 4; ++j) acc[i][j] = (f32x4)(0.0f);

    // staging geometry: LDS short offset t*8 == row-major [row=t>>2][k=(t&3)*8]
    int arow = t >> 2;            // 0..63
    int acol = (t & 3) * 8;       // 0,8,16,24 (elements)
    const float* Ag0 = X + (size_t)(m0 + arow) * K_TOTAL + acol;
    const float* Ag1 = Ag0 + (size_t)64 * K_TOTAL;
    const __hip_bfloat16* Bg0 = Wb + (size_t)(n0 + arow) * K_TOTAL + acol;   // PRE
    const __hip_bfloat16* Bg1 = Bg0 + (size_t)64 * K_TOTAL;
    // fused path: thread -> (row t>>1, half t&1) = 8 packed words = 16 bf16
    int prow = t >> 1, phalf = t & 1;
    const int* Pg = pw + (size_t)(n0 + prow) * 2048 + phalf * 8;             // !PRE

    float4 xa0, xa1, xb0, xb1;     // A prefetch (8 f32 per 64-row half)
    int4 pb0, pb1;                 // B prefetch (PRE: bf16x8 x2)
    int4 pq0, pq1;                 // B prefetch (!PRE: 8 words)
    float s = 0.0f;

    // iteration-0 loads
    xa0 = *(const float4*)(Ag0);
    xa1 = *(const float4*)(Ag0 + 4);
    xb0 = *(const float4*)(Ag1);
    xb1 = *(const float4*)(Ag1 + 4);
    if (PRE) {
        pb0 = *(const int4*)(Bg0);
        pb1 = *(const int4*)(Bg1);
    } else {
        pq0 = *(const int4*)(Pg);
        pq1 = *(const int4*)(Pg + 4);
        s = sc[(n0 + prow) * 128];
    }

    for (int kt = 0; kt < K_TOTAL / 32; ++kt) {
        if (kt) __syncthreads();          // previous tile's readers done
        // ---- convert + write staged regs to LDS ----
        {
            __hip_bfloat162 oa[4] = {
                __float22bfloat162_rn(make_float2(xa0.x, xa0.y)),
                __float22bfloat162_rn(make_float2(xa0.z, xa0.w)),
                __float22bfloat162_rn(make_float2(xa1.x, xa1.y)),
                __float22bfloat162_rn(make_float2(xa1.z, xa1.w))};
            __hip_bfloat162 ob[4] = {
                __float22bfloat162_rn(make_float2(xb0.x, xb0.y)),
                __float22bfloat162_rn(make_float2(xb0.z, xb0.w)),
                __float22bfloat162_rn(make_float2(xb1.x, xb1.y)),
                __float22bfloat162_rn(make_float2(xb1.z, xb1.w))};
            *(int4*)&As[t * 8] = *(int4*)&oa[0];
            *(int4*)&As[2048 + t * 8] = *(int4*)&ob[0];
        }
        if (PRE) {
            *(int4*)&Bs[t * 8] = pb0;
            *(int4*)&Bs[2048 + t * 8] = pb1;
        } else {
            float ns8 = -8.0f * s;
            int w[8] = {pq0.x, pq0.y, pq0.z, pq0.w, pq1.x, pq1.y, pq1.z, pq1.w};
            __hip_bfloat162 o[8];
#pragma unroll
            for (int i = 0; i < 8; ++i) {
                float lo = fmaf((float)(w[i] & 15), s, ns8);
                float hi = fmaf((float)(w[i] >> 4), s, ns8);
                o[i] = __float22bfloat162_rn(make_float2(lo, hi));
            }
            *(int4*)&Bs[prow * 32 + phalf * 16] = *(int4*)&o[0];
            *(int4*)&Bs[prow * 32 + phalf * 16 + 8] = *(int4*)&o[4];
        }
        __syncthreads();

        // ---- prefetch next tile (in flight during MFMA below) ----
        if (kt < K_TOTAL / 32 - 1) {
            int ko = (kt + 1) * 32;
            xa0 = *(const float4*)(Ag0 + ko);
            xa1 = *(const float4*)(Ag0 + ko + 4);
            xb0 = *(const float4*)(Ag1 + ko);
            xb1 = *(const float4*)(Ag1 + ko + 4);
            if (PRE) {
                pb0 = *(const int4*)(Bg0 + ko);
                pb1 = *(const int4*)(Bg1 + ko);
            } else {
                pq0 = *(const int4*)(Pg + (kt + 1) * 16);
                pq1 = *(const int4*)(Pg + (kt + 1) * 16 + 4);
                s = sc[(n0 + prow) * 128 + kt + 1];
            }
        }

        // ---- compute: 8 ds_read_b128 + 16 MFMA per wave ----
        bf16x8 a[4], b[4];
        int ro = (lane & 15) * 32 + (lane >> 4) * 8;
#pragma unroll
        for (int i = 0; i < 4; ++i)
            a[i] = *(const bf16x8*)&As[(wr * 64 + i * 16) * 32 + ro];
#pragma unroll
        for (int j = 0; j < 4; ++j)
            b[j] = *(const bf16x8*)&Bs[(wc * 64 + j * 16) * 32 + ro];
#pragma unroll
        for (int i = 0; i < 4; ++i)
#pragma unroll
            for (int j = 0; j < 4; ++j)
                acc[i][j] = __builtin_amdgcn_mfma_f32_16x16x32_bf16(a[i], b[j], acc[i][j], 0, 0, 0);
    }

    // ---- epilogue: C/D layout col=lane&15, row=(lane>>4)*4+reg (m89) ----
    int col0 = n0 + wc * 64 + (lane & 15);
    int row0 = m0 + wr * 64 + (lane >> 4) * 4;
#pragma unroll
    for (int i = 0; i < 4; ++i)
#pragma unroll
        for (int j = 0; j < 4; ++j) {
            f32x4 v = acc[i][j];
            int r = row0 + i * 16;
            int c = col0 + j * 16;
#pragma unroll
            for (int q = 0; q < 4; ++q)
                out[(size_t)(r + q) * N_TOTAL + c] = v[q];
        }
}

extern "C" void kernel_launch(void* const* d_in, const int* in_sizes, int n_in,
                              void* d_out, int out_size, void* d_ws, size_t ws_size,
                              hipStream_t stream) {
    const float* X = (const float*)d_in[0];       // float16 ref -> float32 on device
    const int* PW = (const int*)d_in[1];
    const float* SC = (const float*)d_in[2];      // float16 ref -> float32 on device
    float* OUT = (float*)d_out;                   // float16 ref -> float32 on device

    dim3 grid((M_TOTAL / 128) * (N_TOTAL / 128));   // 4096 blocks
    size_t need = (size_t)N_TOTAL * K_TOTAL * sizeof(__hip_bfloat16);  // 33.5 MB

    if (ws_size >= need) {
        __hip_bfloat16* W = (__hip_bfloat16*)d_ws;
        k_dequant<<<dim3(4096), dim3(256), 0, stream>>>(PW, SC, W);
        k_gemm<true><<<grid, dim3(256), 0, stream>>>(X, W, PW, SC, OUT);
    } else {
        k_gemm<false><<<grid, dim3(256), 0, stream>>>(X, nullptr, PW, SC, OUT);
    }
}

// Round 5
// 782.684 us; speedup vs baseline: 1.3374x; 1.3374x over previous
//
#include <hip/hip_runtime.h>
#include <hip/hip_bf16.h>
#include <stdint.h>

#define M_TOTAL 16384
#define N_TOTAL 4096
#define K_TOTAL 4096

typedef __attribute__((ext_vector_type(8))) short bf16x8;
typedef __attribute__((ext_vector_type(4))) float f32x4;

__device__ __forceinline__ void gload_lds16(const void* g, void* l) {
    __builtin_amdgcn_global_load_lds(
        (const __attribute__((address_space(1))) uint32_t*)g,
        (__attribute__((address_space(3))) uint32_t*)l, 16, 0, 0);
}

// ---------------------------------------------------------------------------
// Kernel 0: convert X f32 -> bf16 (134 MB, L3-resident afterwards).
// 1 thread -> 8 elements. 32768 blocks x 256 threads x 8 = 67,108,864 exact.
// ---------------------------------------------------------------------------
__global__ __launch_bounds__(256) void k_convX(const float* __restrict__ X,
                                               __hip_bfloat16* __restrict__ Xb) {
    size_t t = (size_t)blockIdx.x * 256 + threadIdx.x;
    const float* p = X + t * 8;
    float4 a = *(const float4*)p;
    float4 b = *(const float4*)(p + 4);
    __hip_bfloat162 o[4] = {
        __float22bfloat162_rn(make_float2(a.x, a.y)),
        __float22bfloat162_rn(make_float2(a.z, a.w)),
        __float22bfloat162_rn(make_float2(b.x, b.y)),
        __float22bfloat162_rn(make_float2(b.z, b.w))};
    *(int4*)(Xb + t * 8) = *(int4*)&o[0];
}

// ---------------------------------------------------------------------------
// Kernel 1: dequantize packed int4 -> bf16 W[N][K].
// word j of row n: k=2j low nibble, k=2j+1 high nibble; codes 0..15 -> -8..7,
// scaled by scales[n][k/32] (f32 on device). 1 thread -> 8 words -> 16 bf16.
// ---------------------------------------------------------------------------
__global__ __launch_bounds__(256) void k_dequant(const int* __restrict__ pw,
                                                 const float* __restrict__ sc,
                                                 __hip_bfloat16* __restrict__ W) {
    int t = blockIdx.x * 256 + threadIdx.x;
    int row = t >> 8;
    int w0 = (t & 255) << 3;
    const int* p = pw + (size_t)row * 2048 + w0;
    int4 q0 = *(const int4*)p;
    int4 q1 = *(const int4*)(p + 4);
    float s = sc[row * 128 + (w0 >> 4)];
    float ns8 = -8.0f * s;
    int w[8] = {q0.x, q0.y, q0.z, q0.w, q1.x, q1.y, q1.z, q1.w};
    __hip_bfloat162 o[8];
#pragma unroll
    for (int i = 0; i < 8; ++i) {
        float lo = fmaf((float)(w[i] & 15), s, ns8);
        float hi = fmaf((float)(w[i] >> 4), s, ns8);
        o[i] = __float22bfloat162_rn(make_float2(lo, hi));
    }
    __hip_bfloat16* dst = W + (size_t)row * 4096 + w0 * 2;
    *(int4*)dst = *(int4*)&o[0];
    *(int4*)(dst + 8) = *(int4*)&o[4];
}

// ---------------------------------------------------------------------------
// Kernel 2: bf16 GEMM, m97 structure. 128x128 tile, BK=32, 4 waves (2x2),
// 4x4 frags of mfma_f32_16x16x32_bf16. global_load_lds width-16 staging.
// XCD-bijective swizzle (nwg=4096 % 8 == 0).
// AWS=true : A from preconverted bf16 Xb (global_load_lds).
// AWS=false: A reg-staged from f32 X with in-kernel convert (tier B).
// ---------------------------------------------------------------------------
template <bool AWS>
__global__ __launch_bounds__(256) void k_gemm2(const float* __restrict__ X,
                                               const __hip_bfloat16* __restrict__ Xb,
                                               const __hip_bfloat16* __restrict__ Wb,
                                               float* __restrict__ out) {
    __shared__ __align__(16) short As[128 * 32];
    __shared__ __align__(16) short Bs[128 * 32];

    // XCD swizzle: blocks bid%8==x run on XCD x; give them consecutive tiles.
    int bid = blockIdx.x;
    int swz = (bid & 7) * 512 + (bid >> 3);
    int bn = swz & 31;            // N fastest -> 32 consecutive tiles share A panel
    int bm = swz >> 5;
    int m0 = bm * 128, n0 = bn * 128;
    int t = threadIdx.x;
    int lane = t & 63;
    int wv = t >> 6;
    int wr = wv >> 1, wc = wv & 1;

    f32x4 acc[4][4];
#pragma unroll
    for (int i = 0; i < 4; ++i)
#pragma unroll
        for (int j = 0; j < 4; ++j) acc[i][j] = (f32x4)(0.0f);

    // staging: thread t -> row t>>2 (of 64), 16B chunk t&3; LDS dest t*16B
    int arow = t >> 2;
    int acol = (t & 3) * 8;
    const __hip_bfloat16* Agb0 = Xb + (size_t)(m0 + arow) * K_TOTAL + acol;
    const __hip_bfloat16* Agb1 = Agb0 + (size_t)64 * K_TOTAL;
    const float* Agf0 = X + (size_t)(m0 + arow) * K_TOTAL + acol;
    const float* Agf1 = Agf0 + (size_t)64 * K_TOTAL;
    const __hip_bfloat16* Bg0 = Wb + (size_t)(n0 + arow) * K_TOTAL + acol;
    const __hip_bfloat16* Bg1 = Bg0 + (size_t)64 * K_TOTAL;

    float4 xa0, xa1, xb0, xb1;   // tier-B A prefetch
    if (!AWS) {
        xa0 = *(const float4*)(Agf0);
        xa1 = *(const float4*)(Agf0 + 4);
        xb0 = *(const float4*)(Agf1);
        xb1 = *(const float4*)(Agf1 + 4);
    }

    for (int kt = 0; kt < K_TOTAL / 32; ++kt) {
        if (kt) __syncthreads();          // previous tile's readers done
        if (AWS) {
            gload_lds16(Agb0 + kt * 32, &As[t * 8]);
            gload_lds16(Agb1 + kt * 32, &As[2048 + t * 8]);
        } else {
            __hip_bfloat162 oa[4] = {
                __float22bfloat162_rn(make_float2(xa0.x, xa0.y)),
                __float22bfloat162_rn(make_float2(xa0.z, xa0.w)),
                __float22bfloat162_rn(make_float2(xa1.x, xa1.y)),
                __float22bfloat162_rn(make_float2(xa1.z, xa1.w))};
            __hip_bfloat162 ob[4] = {
                __float22bfloat162_rn(make_float2(xb0.x, xb0.y)),
                __float22bfloat162_rn(make_float2(xb0.z, xb0.w)),
                __float22bfloat162_rn(make_float2(xb1.x, xb1.y)),
                __float22bfloat162_rn(make_float2(xb1.z, xb1.w))};
            *(int4*)&As[t * 8] = *(int4*)&oa[0];
            *(int4*)&As[2048 + t * 8] = *(int4*)&ob[0];
        }
        gload_lds16(Bg0 + kt * 32, &Bs[t * 8]);
        gload_lds16(Bg1 + kt * 32, &Bs[2048 + t * 8]);
        __syncthreads();                  // compiler drains vmcnt(0) here

        if (!AWS && kt < K_TOTAL / 32 - 1) {
            int ko = (kt + 1) * 32;
            xa0 = *(const float4*)(Agf0 + ko);
            xa1 = *(const float4*)(Agf0 + ko + 4);
            xb0 = *(const float4*)(Agf1 + ko);
            xb1 = *(const float4*)(Agf1 + ko + 4);
        }

        // ---- compute: 8 ds_read_b128 + 16 MFMA per wave ----
        bf16x8 a[4], b[4];
        int ro = (lane & 15) * 32 + (lane >> 4) * 8;
#pragma unroll
        for (int i = 0; i < 4; ++i)
            a[i] = *(const bf16x8*)&As[(wr * 64 + i * 16) * 32 + ro];
#pragma unroll
        for (int j = 0; j < 4; ++j)
            b[j] = *(const bf16x8*)&Bs[(wc * 64 + j * 16) * 32 + ro];
#pragma unroll
        for (int i = 0; i < 4; ++i)
#pragma unroll
            for (int j = 0; j < 4; ++j)
                acc[i][j] = __builtin_amdgcn_mfma_f32_16x16x32_bf16(a[i], b[j], acc[i][j], 0, 0, 0);
    }

    // ---- epilogue: C/D layout col=lane&15, row=(lane>>4)*4+reg ----
    int col0 = n0 + wc * 64 + (lane & 15);
    int row0 = m0 + wr * 64 + (lane >> 4) * 4;
#pragma unroll
    for (int i = 0; i < 4; ++i)
#pragma unroll
        for (int j = 0; j < 4; ++j) {
            f32x4 v = acc[i][j];
            int r = row0 + i * 16;
            int c = col0 + j * 16;
#pragma unroll
            for (int q = 0; q < 4; ++q)
                out[(size_t)(r + q) * N_TOTAL + c] = v[q];
        }
}

// ---------------------------------------------------------------------------
// Tier C fallback: fully fused (round-4 verified), no workspace needed.
// ---------------------------------------------------------------------------
__global__ __launch_bounds__(256) void k_gemm_fused(const float* __restrict__ X,
                                                    const int* __restrict__ pw,
                                                    const float* __restrict__ sc,
                                                    float* __restrict__ out) {
    __shared__ __align__(16) short As[128 * 32];
    __shared__ __align__(16) short Bs[128 * 32];

    int bid = blockIdx.x;
    int bn = bid & 31;
    int bm = bid >> 5;
    int m0 = bm * 128, n0 = bn * 128;
    int t = threadIdx.x;
    int lane = t & 63;
    int wv = t >> 6;
    int wr = wv >> 1, wc = wv & 1;

    f32x4 acc[4][4];
#pragma unroll
    for (int i = 0; i < 4; ++i)
#pragma unroll
        for (int j = 0; j < 4; ++j) acc[i][j] = (f32x4)(0.0f);

    int arow = t >> 2;
    int acol = (t & 3) * 8;
    const float* Ag0 = X + (size_t)(m0 + arow) * K_TOTAL + acol;
    const float* Ag1 = Ag0 + (size_t)64 * K_TOTAL;
    int prow = t >> 1, phalf = t & 1;
    const int* Pg = pw + (size_t)(n0 + prow) * 2048 + phalf * 8;

    float4 xa0, xa1, xb0, xb1;
    int4 pq0, pq1;
    float s;
    xa0 = *(const float4*)(Ag0);
    xa1 = *(const float4*)(Ag0 + 4);
    xb0 = *(const float4*)(Ag1);
    xb1 = *(const float4*)(Ag1 + 4);
    pq0 = *(const int4*)(Pg);
    pq1 = *(const int4*)(Pg + 4);
    s = sc[(n0 + prow) * 128];

    for (int kt = 0; kt < K_TOTAL / 32; ++kt) {
        if (kt) __syncthreads();
        {
            __hip_bfloat162 oa[4] = {
                __float22bfloat162_rn(make_float2(xa0.x, xa0.y)),
                __float22bfloat162_rn(make_float2(xa0.z, xa0.w)),
                __float22bfloat162_rn(make_float2(xa1.x, xa1.y)),
                __float22bfloat162_rn(make_float2(xa1.z, xa1.w))};
            __hip_bfloat162 ob[4] = {
                __float22bfloat162_rn(make_float2(xb0.x, xb0.y)),
                __float22bfloat162_rn(make_float2(xb0.z, xb0.w)),
                __float22bfloat162_rn(make_float2(xb1.x, xb1.y)),
                __float22bfloat162_rn(make_float2(xb1.z, xb1.w))};
            *(int4*)&As[t * 8] = *(int4*)&oa[0];
            *(int4*)&As[2048 + t * 8] = *(int4*)&ob[0];
        }
        {
            float ns8 = -8.0f * s;
            int w[8] = {pq0.x, pq0.y, pq0.z, pq0.w, pq1.x, pq1.y, pq1.z, pq1.w};
            __hip_bfloat162 o[8];
#pragma unroll
            for (int i = 0; i < 8; ++i) {
                float lo = fmaf((float)(w[i] & 15), s, ns8);
                float hi = fmaf((float)(w[i] >> 4), s, ns8);
                o[i] = __float22bfloat162_rn(make_float2(lo, hi));
            }
            *(int4*)&Bs[prow * 32 + phalf * 16] = *(int4*)&o[0];
            *(int4*)&Bs[prow * 32 + phalf * 16 + 8] = *(int4*)&o[4];
        }
        __syncthreads();

        if (kt < K_TOTAL / 32 - 1) {
            int ko = (kt + 1) * 32;
            xa0 = *(const float4*)(Ag0 + ko);
            xa1 = *(const float4*)(Ag0 + ko + 4);
            xb0 = *(const float4*)(Ag1 + ko);
            xb1 = *(const float4*)(Ag1 + ko + 4);
            pq0 = *(const int4*)(Pg + (kt + 1) * 16);
            pq1 = *(const int4*)(Pg + (kt + 1) * 16 + 4);
            s = sc[(n0 + prow) * 128 + kt + 1];
        }

        bf16x8 a[4], b[4];
        int ro = (lane & 15) * 32 + (lane >> 4) * 8;
#pragma unroll
        for (int i = 0; i < 4; ++i)
            a[i] = *(const bf16x8*)&As[(wr * 64 + i * 16) * 32 + ro];
#pragma unroll
        for (int j = 0; j < 4; ++j)
            b[j] = *(const bf16x8*)&Bs[(wc * 64 + j * 16) * 32 + ro];
#pragma unroll
        for (int i = 0; i < 4; ++i)
#pragma unroll
            for (int j = 0; j < 4; ++j)
                acc[i][j] = __builtin_amdgcn_mfma_f32_16x16x32_bf16(a[i], b[j], acc[i][j], 0, 0, 0);
    }

    int col0 = n0 + wc * 64 + (lane & 15);
    int row0 = m0 + wr * 64 + (lane >> 4) * 4;
#pragma unroll
    for (int i = 0; i < 4; ++i)
#pragma unroll
        for (int j = 0; j < 4; ++j) {
            f32x4 v = acc[i][j];
            int r = row0 + i * 16;
            int c = col0 + j * 16;
#pragma unroll
            for (int q = 0; q < 4; ++q)
                out[(size_t)(r + q) * N_TOTAL + c] = v[q];
        }
}

extern "C" void kernel_launch(void* const* d_in, const int* in_sizes, int n_in,
                              void* d_out, int out_size, void* d_ws, size_t ws_size,
                              hipStream_t stream) {
    const float* X = (const float*)d_in[0];
    const int* PW = (const int*)d_in[1];
    const float* SC = (const float*)d_in[2];
    float* OUT = (float*)d_out;

    dim3 grid((M_TOTAL / 128) * (N_TOTAL / 128));   // 4096 blocks
    const size_t needW = (size_t)N_TOTAL * K_TOTAL * 2;            // 33.5 MB
    const size_t needX = needW + (size_t)M_TOTAL * K_TOTAL * 2;    // +134 MB

    if (ws_size >= needX) {
        __hip_bfloat16* Wb = (__hip_bfloat16*)d_ws;
        __hip_bfloat16* Xb = (__hip_bfloat16*)((char*)d_ws + needW);
        k_convX<<<dim3(32768), dim3(256), 0, stream>>>(X, Xb);
        k_dequant<<<dim3(4096), dim3(256), 0, stream>>>(PW, SC, Wb);
        k_gemm2<true><<<grid, dim3(256), 0, stream>>>(X, Xb, Wb, OUT);
    } else if (ws_size >= needW) {
        __hip_bfloat16* Wb = (__hip_bfloat16*)d_ws;
        k_dequant<<<dim3(4096), dim3(256), 0, stream>>>(PW, SC, Wb);
        k_gemm2<false><<<grid, dim3(256), 0, stream>>>(X, nullptr, Wb, OUT);
    } else {
        k_gemm_fused<<<grid, dim3(256), 0, stream>>>(X, PW, SC, OUT);
    }
}

// Round 6
// 653.805 us; speedup vs baseline: 1.6011x; 1.1971x over previous
//
#include <hip/hip_runtime.h>
#include <hip/hip_bf16.h>
#include <stdint.h>

#define M_TOTAL 16384
#define N_TOTAL 4096
#define K_TOTAL 4096
#define NT (K_TOTAL / 32)

typedef __attribute__((ext_vector_type(8))) short bf16x8;
typedef __attribute__((ext_vector_type(4))) float f32x4;

__device__ __forceinline__ void gload_lds16(const void* g, void* l) {
    __builtin_amdgcn_global_load_lds(
        (const __attribute__((address_space(1))) uint32_t*)g,
        (__attribute__((address_space(3))) uint32_t*)l, 16, 0, 0);
}

// ---------------------------------------------------------------------------
// Kernel 0: X f32 -> bf16 (134 MB, L3-resident afterwards).
// ---------------------------------------------------------------------------
__global__ __launch_bounds__(256) void k_convX(const float* __restrict__ X,
                                               __hip_bfloat16* __restrict__ Xb) {
    size_t t = (size_t)blockIdx.x * 256 + threadIdx.x;
    const float* p = X + t * 8;
    float4 a = *(const float4*)p;
    float4 b = *(const float4*)(p + 4);
    __hip_bfloat162 o[4] = {
        __float22bfloat162_rn(make_float2(a.x, a.y)),
        __float22bfloat162_rn(make_float2(a.z, a.w)),
        __float22bfloat162_rn(make_float2(b.x, b.y)),
        __float22bfloat162_rn(make_float2(b.z, b.w))};
    *(int4*)(Xb + t * 8) = *(int4*)&o[0];
}

// ---------------------------------------------------------------------------
// Kernel 1: packed int4 -> bf16 W[N][K]. word j of row n: k=2j lo nibble,
// k=2j+1 hi nibble; codes 0..15 -> -8..7, scale[n][k/32] (f32).
// ---------------------------------------------------------------------------
__global__ __launch_bounds__(256) void k_dequant(const int* __restrict__ pw,
                                                 const float* __restrict__ sc,
                                                 __hip_bfloat16* __restrict__ W) {
    int t = blockIdx.x * 256 + threadIdx.x;
    int row = t >> 8;
    int w0 = (t & 255) << 3;
    const int* p = pw + (size_t)row * 2048 + w0;
    int4 q0 = *(const int4*)p;
    int4 q1 = *(const int4*)(p + 4);
    float s = sc[row * 128 + (w0 >> 4)];
    float ns8 = -8.0f * s;
    int w[8] = {q0.x, q0.y, q0.z, q0.w, q1.x, q1.y, q1.z, q1.w};
    __hip_bfloat162 o[8];
#pragma unroll
    for (int i = 0; i < 8; ++i) {
        float lo = fmaf((float)(w[i] & 15), s, ns8);
        float hi = fmaf((float)(w[i] >> 4), s, ns8);
        o[i] = __float22bfloat162_rn(make_float2(lo, hi));
    }
    __hip_bfloat16* dst = W + (size_t)row * 4096 + w0 * 2;
    *(int4*)dst = *(int4*)&o[0];
    *(int4*)(dst + 8) = *(int4*)&o[4];
}

// ---------------------------------------------------------------------------
// Kernel 2 (tier A): 256x256 tile, BK=32, ring of 4 LDS buffers, 512 thr
// (8 waves 2Mx4N), per-wave 128x64 out = 8x4 frags of mfma 16x16x32.
// Per tile: 2 phases {ds_read | 2x global_load_lds for tile t+3 | barrier |
// setprio+16 MFMA | barrier}; counted vmcnt(8) once per tile (never 0).
//
// LDS layout (conflict-free): per 8-row x 64B group, 16B slot index
// s = chunk*8 + row%8 (column-major) -> a frag-read's same-chunk lanes span
// a contiguous 128B = all 32 banks. global_load_lds writes linearly; the
// GLOBAL source address carries the permutation (slot i -> global row
// (i>>5)*8+(i&7), k-chunk (i>>3)&3), keeping 64B/row coalescing.
// ---------------------------------------------------------------------------
__global__ __launch_bounds__(512, 2) void k_gemm3(const __hip_bfloat16* __restrict__ Xb,
                                                  const __hip_bfloat16* __restrict__ Wb,
                                                  float* __restrict__ out) {
    __shared__ __align__(16) short L[4][2][8192];   // 4 bufs x {A,B} x 16 KiB = 128 KiB

    int bid = blockIdx.x;
    int swz = (bid & 7) * 128 + (bid >> 3);         // XCD-bijective (1024 % 8 == 0)
    int bn = swz & 15, bm = swz >> 4;               // N fastest: 16 blocks share A panel
    int m0 = bm * 256, n0 = bn * 256;
    int t = threadIdx.x, lane = t & 63, wv = t >> 6;
    int wm = wv >> 2, wn = wv & 3;

    // staging: slot t -> global (row (t>>5)*8+(t&7), chunk (t>>3)&3); slot t+512 -> +128 rows
    int srow = (t >> 5) * 8 + (t & 7);
    int schk = (t >> 3) & 3;
    const __hip_bfloat16* gA0 = Xb + (size_t)(m0 + srow) * K_TOTAL + schk * 8;
    const __hip_bfloat16* gA1 = gA0 + (size_t)128 * K_TOTAL;
    const __hip_bfloat16* gB0 = Wb + (size_t)(n0 + srow) * K_TOTAL + schk * 8;
    const __hip_bfloat16* gB1 = gB0 + (size_t)128 * K_TOTAL;

    // frag-read lane offset (shorts): row r=R+(lane&15), chunk c=lane>>4
    // addr = (r>>3)*256 + (c*8 + (r&7))*8 ; R*32 factored out
    int offL = ((lane & 15) >> 3) * 256 + ((lane >> 4) * 8 + (lane & 7)) * 8;

    f32x4 acc[8][4];
#pragma unroll
    for (int f = 0; f < 8; ++f)
#pragma unroll
        for (int j = 0; j < 4; ++j) acc[f][j] = (f32x4)(0.0f);

    // ---- prologue: stage tiles 0,1,2 (12 gloads); wait tile0 (oldest 4) ----
#pragma unroll
    for (int tt = 0; tt < 3; ++tt) {
        gload_lds16(gA0 + tt * 32, &L[tt][0][t * 8]);
        gload_lds16(gA1 + tt * 32, &L[tt][0][4096 + t * 8]);
        gload_lds16(gB0 + tt * 32, &L[tt][1][t * 8]);
        gload_lds16(gB1 + tt * 32, &L[tt][1][4096 + t * 8]);
    }
    asm volatile("s_waitcnt vmcnt(8)" ::: "memory");
    __builtin_amdgcn_s_barrier();

    for (int kt = 0; kt < NT; ++kt) {
        int cb = kt & 3;
        const short* LA = &L[cb][0][0];
        const short* LB = &L[cb][1][0];
        bool pf = (kt + 3) < NT;
        int bp = (kt + 3) & 3;
        int pko = (kt + 3) * 32;

        // ================= phase A =================
        bf16x8 a[4], bb[4];
#pragma unroll
        for (int f = 0; f < 4; ++f)
            a[f] = *(const bf16x8*)&LA[(wm * 128 + f * 16) * 32 + offL];
#pragma unroll
        for (int f = 0; f < 4; ++f)
            bb[f] = *(const bf16x8*)&LB[(wn * 64 + f * 16) * 32 + offL];
        if (pf) {   // A-half of tile kt+3 -> buf bp (== buf kt-1, freed last tile)
            gload_lds16(gA0 + pko, &L[bp][0][t * 8]);
            gload_lds16(gA1 + pko, &L[bp][0][4096 + t * 8]);
        }
        __builtin_amdgcn_s_barrier();
        __builtin_amdgcn_s_setprio(1);
#pragma unroll
        for (int f = 0; f < 4; ++f)
#pragma unroll
            for (int j = 0; j < 4; ++j)
                acc[f][j] = __builtin_amdgcn_mfma_f32_16x16x32_bf16(a[f], bb[j], acc[f][j], 0, 0, 0);
        __builtin_amdgcn_s_setprio(0);
        __builtin_amdgcn_s_barrier();

        // ================= phase B =================
        bf16x8 a2[4];
#pragma unroll
        for (int f = 0; f < 4; ++f)
            a2[f] = *(const bf16x8*)&LA[(wm * 128 + 64 + f * 16) * 32 + offL];
        if (pf) {   // B-half of tile kt+3
            gload_lds16(gB0 + pko, &L[bp][1][t * 8]);
            gload_lds16(gB1 + pko, &L[bp][1][4096 + t * 8]);
        }
        __builtin_amdgcn_s_barrier();
        __builtin_amdgcn_s_setprio(1);
#pragma unroll
        for (int f = 0; f < 4; ++f)
#pragma unroll
            for (int j = 0; j < 4; ++j)
                acc[4 + f][j] = __builtin_amdgcn_mfma_f32_16x16x32_bf16(a2[f], bb[j], acc[4 + f][j], 0, 0, 0);
        __builtin_amdgcn_s_setprio(0);

        // ---- tile boundary: require tile kt+1 landed; keep newer in flight ----
        if (kt < NT - 1) {
            if (kt <= NT - 4)      asm volatile("s_waitcnt vmcnt(8)" ::: "memory");
            else if (kt == NT - 3) asm volatile("s_waitcnt vmcnt(4)" ::: "memory");
            else                   asm volatile("s_waitcnt vmcnt(0)" ::: "memory");
            __builtin_amdgcn_s_barrier();
        }
    }

    // ---- epilogue: C/D layout col=lane&15, row=(lane>>4)*4+reg ----
    int col0 = n0 + wn * 64 + (lane & 15);
    int row0 = m0 + wm * 128 + (lane >> 4) * 4;
#pragma unroll
    for (int f = 0; f < 8; ++f)
#pragma unroll
        for (int j = 0; j < 4; ++j) {
            f32x4 v = acc[f][j];
            int r = row0 + f * 16;
            int c = col0 + j * 16;
#pragma unroll
            for (int q = 0; q < 4; ++q)
                out[(size_t)(r + q) * N_TOTAL + c] = v[q];
        }
}

// ---------------------------------------------------------------------------
// Tier B: round-5 m97-structure GEMM, A reg-staged from f32 X (verified).
// ---------------------------------------------------------------------------
__global__ __launch_bounds__(256) void k_gemm2b(const float* __restrict__ X,
                                                const __hip_bfloat16* __restrict__ Wb,
                                                float* __restrict__ out) {
    __shared__ __align__(16) short As[128 * 32];
    __shared__ __align__(16) short Bs[128 * 32];
    int bid = blockIdx.x;
    int swz = (bid & 7) * 512 + (bid >> 3);
    int bn = swz & 31, bm = swz >> 5;
    int m0 = bm * 128, n0 = bn * 128;
    int t = threadIdx.x, lane = t & 63, wv = t >> 6;
    int wr = wv >> 1, wc = wv & 1;
    f32x4 acc[4][4];
#pragma unroll
    for (int i = 0; i < 4; ++i)
#pragma unroll
        for (int j = 0; j < 4; ++j) acc[i][j] = (f32x4)(0.0f);
    int arow = t >> 2, acol = (t & 3) * 8;
    const float* Agf0 = X + (size_t)(m0 + arow) * K_TOTAL + acol;
    const float* Agf1 = Agf0 + (size_t)64 * K_TOTAL;
    const __hip_bfloat16* Bg0 = Wb + (size_t)(n0 + arow) * K_TOTAL + acol;
    const __hip_bfloat16* Bg1 = Bg0 + (size_t)64 * K_TOTAL;
    float4 xa0 = *(const float4*)(Agf0), xa1 = *(const float4*)(Agf0 + 4);
    float4 xb0 = *(const float4*)(Agf1), xb1 = *(const float4*)(Agf1 + 4);
    for (int kt = 0; kt < NT; ++kt) {
        if (kt) __syncthreads();
        __hip_bfloat162 oa[4] = {
            __float22bfloat162_rn(make_float2(xa0.x, xa0.y)),
            __float22bfloat162_rn(make_float2(xa0.z, xa0.w)),
            __float22bfloat162_rn(make_float2(xa1.x, xa1.y)),
            __float22bfloat162_rn(make_float2(xa1.z, xa1.w))};
        __hip_bfloat162 ob[4] = {
            __float22bfloat162_rn(make_float2(xb0.x, xb0.y)),
            __float22bfloat162_rn(make_float2(xb0.z, xb0.w)),
            __float22bfloat162_rn(make_float2(xb1.x, xb1.y)),
            __float22bfloat162_rn(make_float2(xb1.z, xb1.w))};
        *(int4*)&As[t * 8] = *(int4*)&oa[0];
        *(int4*)&As[2048 + t * 8] = *(int4*)&ob[0];
        gload_lds16(Bg0 + kt * 32, &Bs[t * 8]);
        gload_lds16(Bg1 + kt * 32, &Bs[2048 + t * 8]);
        __syncthreads();
        if (kt < NT - 1) {
            int ko = (kt + 1) * 32;
            xa0 = *(const float4*)(Agf0 + ko);
            xa1 = *(const float4*)(Agf0 + ko + 4);
            xb0 = *(const float4*)(Agf1 + ko);
            xb1 = *(const float4*)(Agf1 + ko + 4);
        }
        bf16x8 a[4], b[4];
        int ro = (lane & 15) * 32 + (lane >> 4) * 8;
#pragma unroll
        for (int i = 0; i < 4; ++i)
            a[i] = *(const bf16x8*)&As[(wr * 64 + i * 16) * 32 + ro];
#pragma unroll
        for (int j = 0; j < 4; ++j)
            b[j] = *(const bf16x8*)&Bs[(wc * 64 + j * 16) * 32 + ro];
#pragma unroll
        for (int i = 0; i < 4; ++i)
#pragma unroll
            for (int j = 0; j < 4; ++j)
                acc[i][j] = __builtin_amdgcn_mfma_f32_16x16x32_bf16(a[i], b[j], acc[i][j], 0, 0, 0);
    }
    int col0 = n0 + wc * 64 + (lane & 15);
    int row0 = m0 + wr * 64 + (lane >> 4) * 4;
#pragma unroll
    for (int i = 0; i < 4; ++i)
#pragma unroll
        for (int j = 0; j < 4; ++j) {
            f32x4 v = acc[i][j];
            int r = row0 + i * 16, c = col0 + j * 16;
#pragma unroll
            for (int q = 0; q < 4; ++q)
                out[(size_t)(r + q) * N_TOTAL + c] = v[q];
        }
}

extern "C" void kernel_launch(void* const* d_in, const int* in_sizes, int n_in,
                              void* d_out, int out_size, void* d_ws, size_t ws_size,
                              hipStream_t stream) {
    const float* X = (const float*)d_in[0];
    const int* PW = (const int*)d_in[1];
    const float* SC = (const float*)d_in[2];
    float* OUT = (float*)d_out;

    const size_t needW = (size_t)N_TOTAL * K_TOTAL * 2;            // 33.5 MB
    const size_t needX = needW + (size_t)M_TOTAL * K_TOTAL * 2;    // +134 MB

    if (ws_size >= needX) {
        __hip_bfloat16* Wb = (__hip_bfloat16*)d_ws;
        __hip_bfloat16* Xb = (__hip_bfloat16*)((char*)d_ws + needW);
        k_convX<<<dim3(32768), dim3(256), 0, stream>>>(X, Xb);
        k_dequant<<<dim3(4096), dim3(256), 0, stream>>>(PW, SC, Wb);
        k_gemm3<<<dim3((M_TOTAL / 256) * (N_TOTAL / 256)), dim3(512), 0, stream>>>(Xb, Wb, OUT);
    } else if (ws_size >= needW) {
        __hip_bfloat16* Wb = (__hip_bfloat16*)d_ws;
        k_dequant<<<dim3(4096), dim3(256), 0, stream>>>(PW, SC, Wb);
        k_gemm2b<<<dim3((M_TOTAL / 128) * (N_TOTAL / 128)), dim3(256), 0, stream>>>(X, Wb, OUT);
    }
    // note: harness-guaranteed ws is >= needW in this problem (verified rounds 4-5)
}